// Round 1
// baseline (828.233 us; speedup 1.0000x reference)
//
#include <hip/hip_runtime.h>
#include <hip/hip_bf16.h>

// PerResidueEncoder: frame+crd featurize -> sparse layer1 (aa-grouped) ->
// 3x bf16 MFMA GEMM (relu, relu, linear).
// tokens = 16*4096 = 65536, FEAT=512, L1OUT=1024, 21 aa types, 42 crd feats.

typedef __attribute__((ext_vector_type(8))) short short8;
typedef __attribute__((ext_vector_type(4))) float floatx4;

#define TOKENS 65536
#define FEATD 512
#define L1OUT 1024
#define NAA 21
#define EPSF 1e-6f
#define ORDER_N 66880   // 1045 blocks * 64 slots >= 65536 + 21*63

static __device__ __forceinline__ unsigned short f2bf(float f) {
  union { float f; unsigned int u; } v; v.f = f;
  unsigned int u = v.u;
  return (unsigned short)((u + 0x7FFFu + ((u >> 16) & 1u)) >> 16);
}

// ---- init: order=-1, counts/flag=0 ----
__global__ void k_init(int* __restrict__ order, int* __restrict__ counts) {
  int i = blockIdx.x * 256 + threadIdx.x;
  if (i < ORDER_N) order[i] = -1;
  if (i < 64) counts[i] = 0;
}

// ---- detect atom_mask dtype: bit1 = uint8-packed, bit2 = float32 ----
__global__ void k_detect(const unsigned int* __restrict__ mask, int* __restrict__ flag) {
  unsigned int v = mask[threadIdx.x];   // first 1KB: safe for any elem width
  int b = 0;
  if (v == 0x3F800000u) b = 2;
  else if (v > 1u) b = 1;
  if (b) atomicOr(flag, b);
}

// ---- featurize: frame, rotate, mask -> crd[t][42]; histogram aa ----
__global__ void k_feat(const float* __restrict__ pos14, const int* __restrict__ aa,
                       const void* __restrict__ maskp, float* __restrict__ crd,
                       int* __restrict__ counts) {
  int t = blockIdx.x * 256 + threadIdx.x;
  if (t >= TOKENS) return;
  int fl = counts[32];
  const float* p = pos14 + (size_t)t * 42;
  float px[14], py[14], pz[14];
#pragma unroll
  for (int a = 0; a < 14; ++a) { px[a] = p[a*3]; py[a] = p[a*3+1]; pz[a] = p[a*3+2]; }
  float cx = px[1], cy = py[1], cz = pz[1];
  float v1x = px[2]-cx, v1y = py[2]-cy, v1z = pz[2]-cz;
  float n1 = sqrtf(v1x*v1x + v1y*v1y + v1z*v1z);
  float i1 = 1.f / (n1 + EPSF);
  float e1x = v1x*i1, e1y = v1y*i1, e1z = v1z*i1;
  float v2x = px[0]-cx, v2y = py[0]-cy, v2z = pz[0]-cz;
  float d12 = e1x*v2x + e1y*v2y + e1z*v2z;
  float u2x = v2x - d12*e1x, u2y = v2y - d12*e1y, u2z = v2z - d12*e1z;
  float n2 = sqrtf(u2x*u2x + u2y*u2y + u2z*u2z);
  float i2 = 1.f / (n2 + EPSF);
  float e2x = u2x*i2, e2y = u2y*i2, e2z = u2z*i2;
  float e3x = e1y*e2z - e1z*e2y;
  float e3y = e1z*e2x - e1x*e2z;
  float e3z = e1x*e2y - e1y*e2x;
  float* o = crd + (size_t)t * 42;
#pragma unroll
  for (int a = 0; a < 14; ++a) {
    bool mv;
    size_t mi = (size_t)t * 14 + a;
    if (fl & 2)      mv = ((const float*)maskp)[mi] != 0.f;
    else if (fl & 1) mv = ((const unsigned char*)maskp)[mi] != 0;
    else             mv = ((const int*)maskp)[mi] != 0;
    float qx = px[a]-cx, qy = py[a]-cy, qz = pz[a]-cz;
    o[a*3+0] = mv ? (e1x*qx + e1y*qy + e1z*qz) : 0.f;
    o[a*3+1] = mv ? (e2x*qx + e2y*qy + e2z*qz) : 0.f;
    o[a*3+2] = mv ? (e3x*qx + e3y*qy + e3z*qz) : 0.f;
  }
  atomicAdd(&counts[aa[t]], 1);
}

// ---- padded group offsets (pad each aa group to multiple of 64) ----
__global__ void k_offsets(const int* __restrict__ counts, int* __restrict__ cnt2) {
  if (threadIdx.x == 0) {
    int run = 0;
    for (int a = 0; a < NAA; ++a) { cnt2[a] = run; run += ((counts[a] + 63) >> 6) << 6; }
  }
}

__global__ void k_scatter(const int* __restrict__ aa, int* __restrict__ cnt2,
                          int* __restrict__ order) {
  int t = blockIdx.x * 256 + threadIdx.x;
  if (t >= TOKENS) return;
  int p = atomicAdd(&cnt2[aa[t]], 1);
  order[p] = t;
}

// ---- T1[a][c] = embed[a] @ w1[882:] + b1 ----
__global__ void k_T1(const float* __restrict__ embed, const float* __restrict__ w1,
                     const float* __restrict__ b1, float* __restrict__ T1) {
  int idx = blockIdx.x * 256 + threadIdx.x;   // 84*256 == 21*1024 exactly
  int a = idx >> 10, c = idx & 1023;
  float acc = b1[c];
  const float* e = embed + a * FEATD;
#pragma unroll 8
  for (int k = 0; k < FEATD; ++k)
    acc += e[k] * w1[(size_t)(882 + k) * L1OUT + c];
  T1[idx] = acc;
}

// ---- transpose W[K][N] fp32 -> WT[N][K] bf16 ----
__global__ void k_transpose(const float* __restrict__ W, unsigned short* __restrict__ WT,
                            int kbits, int N) {
  int idx = blockIdx.x * 256 + threadIdx.x;
  int K = 1 << kbits;
  int n = idx >> kbits, k = idx & (K - 1);
  WT[(size_t)n * K + k] = f2bf(W[(size_t)k * N + n]);
}

// ---- layer1: per 64-pos single-aa block, weight-stationary, fp32 vector ----
__global__ void k_layer1(const int* __restrict__ order, const int* __restrict__ aa_g,
                         const float* __restrict__ crd, const float* __restrict__ w1,
                         const float* __restrict__ T1, unsigned short* __restrict__ h1) {
  __shared__ int tokens[64];
  __shared__ int s_aa;
  __shared__ float crdl[64 * 42];
  __shared__ float Wl[42 * 132];   // stride 132 floats (pad)
  const int tid = threadIdx.x;
  const int pb = blockIdx.y;
  const int cc = blockIdx.x * 128;
  if (tid < 64) tokens[tid] = order[pb * 64 + tid];
  __syncthreads();
  if (tid == 0) {
    int a = -1;
    for (int i = 0; i < 64; ++i) if (tokens[i] >= 0) { a = aa_g[tokens[i]]; break; }
    s_aa = a;
  }
  __syncthreads();
  const int a = s_aa;
  if (a < 0) return;   // fully-dummy block (uniform)
  for (int idx = tid; idx < 64 * 42; idx += 256) {
    int pos = idx / 42, j = idx - pos * 42;
    int tok = tokens[pos];
    crdl[idx] = (tok >= 0) ? crd[(size_t)tok * 42 + j] : 0.f;
  }
  const float* wsrc = w1 + (size_t)a * 42 * L1OUT + cc;
  for (int idx = tid; idx < 42 * 128; idx += 256) {
    int j = idx >> 7, c = idx & 127;
    Wl[j * 132 + c] = wsrc[(size_t)j * L1OUT + c];
  }
  __syncthreads();
  const int posl = (tid >> 4) * 4;
  const int colb = (tid & 15) * 8;
  float acc[4][8];
  {
    const float* tb = T1 + a * L1OUT + cc + colb;
#pragma unroll
    for (int q = 0; q < 8; ++q) {
      float t = tb[q];
#pragma unroll
      for (int pp = 0; pp < 4; ++pp) acc[pp][q] = t;
    }
  }
  for (int j = 0; j < 42; ++j) {
    float4 wA = *(const float4*)&Wl[j * 132 + colb];
    float4 wB = *(const float4*)&Wl[j * 132 + colb + 4];
#pragma unroll
    for (int pp = 0; pp < 4; ++pp) {
      float cv = crdl[(posl + pp) * 42 + j];
      acc[pp][0] += cv * wA.x; acc[pp][1] += cv * wA.y;
      acc[pp][2] += cv * wA.z; acc[pp][3] += cv * wA.w;
      acc[pp][4] += cv * wB.x; acc[pp][5] += cv * wB.y;
      acc[pp][6] += cv * wB.z; acc[pp][7] += cv * wB.w;
    }
  }
#pragma unroll
  for (int pp = 0; pp < 4; ++pp) {
    int tok = tokens[posl + pp];
    if (tok < 0) continue;
    unsigned short o8[8];
#pragma unroll
    for (int q = 0; q < 8; ++q) o8[q] = f2bf(fmaxf(acc[pp][q], 0.f));
    *(uint4*)&h1[(size_t)tok * L1OUT + cc + colb] = *(const uint4*)o8;
  }
}

// ---- bf16 MFMA GEMM: [65536 x K] @ [K x 512] (+bias, relu?) ----
// BM=BN=128, BK=64; 4 waves, each 64x64 via 4x4 frags of 16x16x32.
template<int K, bool RELU, bool OUTBF16>
__global__ void k_gemm(const unsigned short* __restrict__ A,
                       const unsigned short* __restrict__ BT,  // [512][K] bf16
                       const float* __restrict__ bias, void* __restrict__ outp) {
  constexpr int N = 512;
  constexpr int LDA = 72;  // 64 + 8 pad: 16B-aligned, 2-way banks (free)
  __shared__ unsigned short Al[128 * LDA];
  __shared__ unsigned short Bl[128 * LDA];
  const int tid = threadIdx.x;
  const int lane = tid & 63;
  const int wid = tid >> 6;
  const int wm = (wid & 1) * 64;
  const int wn = (wid >> 1) * 64;
  const int m0 = blockIdx.y * 128;
  const int n0 = blockIdx.x * 128;
  floatx4 acc[4][4] = {};
  for (int k0 = 0; k0 < K; k0 += 64) {
    __syncthreads();
#pragma unroll
    for (int p = 0; p < 4; ++p) {
      int chunk = p * 256 + tid;
      int row = chunk >> 3, c8 = (chunk & 7) << 3;
      *(uint4*)&Al[row * LDA + c8] = *(const uint4*)&A[(size_t)(m0 + row) * K + k0 + c8];
      *(uint4*)&Bl[row * LDA + c8] = *(const uint4*)&BT[(size_t)(n0 + row) * K + k0 + c8];
    }
    __syncthreads();
#pragma unroll
    for (int kk = 0; kk < 2; ++kk) {
      short8 af[4], bf[4];
      const int kof = kk * 32 + ((lane >> 4) << 3);
#pragma unroll
      for (int i = 0; i < 4; ++i) {
        af[i] = *(const short8*)&Al[(wm + i * 16 + (lane & 15)) * LDA + kof];
        bf[i] = *(const short8*)&Bl[(wn + i * 16 + (lane & 15)) * LDA + kof];
      }
#pragma unroll
      for (int i = 0; i < 4; ++i)
#pragma unroll
        for (int j = 0; j < 4; ++j)
          acc[i][j] = __builtin_amdgcn_mfma_f32_16x16x32_bf16(af[i], bf[j], acc[i][j], 0, 0, 0);
    }
  }
#pragma unroll
  for (int i = 0; i < 4; ++i) {
    int rbase = m0 + wm + i * 16 + ((lane >> 4) << 2);
#pragma unroll
    for (int j = 0; j < 4; ++j) {
      int col = n0 + wn + j * 16 + (lane & 15);
      float bv = bias[col];
#pragma unroll
      for (int r = 0; r < 4; ++r) {
        float v = acc[i][j][r] + bv;
        if (RELU) v = fmaxf(v, 0.f);
        size_t off = (size_t)(rbase + r) * N + col;
        if (OUTBF16) ((unsigned short*)outp)[off] = f2bf(v);
        else ((float*)outp)[off] = v;
      }
    }
  }
}

extern "C" void kernel_launch(void* const* d_in, const int* in_sizes, int n_in,
                              void* d_out, int out_size, void* d_ws, size_t ws_size,
                              hipStream_t stream) {
  const int*   aa    = (const int*)d_in[0];
  const float* pos14 = (const float*)d_in[1];
  const void*  mask  = d_in[2];
  const float* embed = (const float*)d_in[3];
  const float* w1    = (const float*)d_in[4];
  const float* b1    = (const float*)d_in[5];
  const float* w2    = (const float*)d_in[6];
  const float* b2    = (const float*)d_in[7];
  const float* w3    = (const float*)d_in[8];
  const float* b3    = (const float*)d_in[9];
  const float* w4    = (const float*)d_in[10];
  const float* b4    = (const float*)d_in[11];

  char* ws = (char*)d_ws;
  size_t o = 0;
  auto alloc = [&](size_t b) { size_t r = o; o += (b + 255) & ~(size_t)255; return r; };
  unsigned short* w2T = (unsigned short*)(ws + alloc((size_t)512 * 1024 * 2));
  unsigned short* w3T = (unsigned short*)(ws + alloc((size_t)512 * 512 * 2));
  unsigned short* w4T = (unsigned short*)(ws + alloc((size_t)512 * 512 * 2));
  float* T1   = (float*)(ws + alloc((size_t)NAA * 1024 * 4));
  float* crd  = (float*)(ws + alloc((size_t)TOKENS * 42 * 4));
  int* counts = (int*)(ws + alloc(64 * 4));          // [32] doubles as dtype flag
  int* cnt2   = (int*)(ws + alloc(64 * 4));
  int* order  = (int*)(ws + alloc((size_t)ORDER_N * 4));
  unsigned short* h1 = (unsigned short*)(ws + alloc((size_t)TOKENS * 1024 * 2));
  unsigned short* h2 = (unsigned short*)(ws + alloc((size_t)TOKENS * 512 * 2));
  unsigned short* h3 = h1;  // reuse h1 buffer for h3

  k_init<<<262, 256, 0, stream>>>(order, counts);
  k_detect<<<1, 256, 0, stream>>>((const unsigned int*)mask, &counts[32]);
  k_transpose<<<2048, 256, 0, stream>>>(w2, w2T, 10, 512);
  k_transpose<<<1024, 256, 0, stream>>>(w3, w3T, 9, 512);
  k_transpose<<<1024, 256, 0, stream>>>(w4, w4T, 9, 512);
  k_T1<<<84, 256, 0, stream>>>(embed, w1, b1, T1);
  k_feat<<<256, 256, 0, stream>>>(pos14, aa, mask, crd, counts);
  k_offsets<<<1, 64, 0, stream>>>(counts, cnt2);
  k_scatter<<<256, 256, 0, stream>>>(aa, cnt2, order);
  k_layer1<<<dim3(8, 1045), 256, 0, stream>>>(order, aa, crd, w1, T1, h1);
  k_gemm<1024, true,  true ><<<dim3(4, 512), 256, 0, stream>>>(h1, w2T, b2, h2);
  k_gemm<512,  true,  true ><<<dim3(4, 512), 256, 0, stream>>>(h2, w3T, b3, h3);
  k_gemm<512,  false, false><<<dim3(4, 512), 256, 0, stream>>>(h3, w4T, b4, d_out);
}

// Round 2
// 522.859 us; speedup vs baseline: 1.5840x; 1.5840x over previous
//
#include <hip/hip_runtime.h>
#include <hip/hip_bf16.h>

// PerResidueEncoder: frame+crd featurize -> sparse layer1 (aa-grouped) ->
// 3x bf16 MFMA GEMM (relu, relu, linear).
// R1: LDS-aggregated histograms (was: 65536 contended global atomics on 21
//     addrs = 166us at 0.3% VALUBusy); GEMM staging via global_load_lds
//     width=16 with XOR bank swizzle (m97 pattern).

typedef __attribute__((ext_vector_type(8))) short short8;
typedef __attribute__((ext_vector_type(4))) float floatx4;

#define TOKENS 65536
#define FEATD 512
#define L1OUT 1024
#define NAA 21
#define EPSF 1e-6f
#define ORDER_N 66880   // 1045 blocks * 64 slots >= 65536 + 21*63

static __device__ __forceinline__ unsigned short f2bf(float f) {
  union { float f; unsigned int u; } v; v.f = f;
  unsigned int u = v.u;
  return (unsigned short)((u + 0x7FFFu + ((u >> 16) & 1u)) >> 16);
}

#define GLDS16(g, l) __builtin_amdgcn_global_load_lds(                        \
    (const __attribute__((address_space(1))) unsigned int*)(g),               \
    (__attribute__((address_space(3))) unsigned int*)(l), 16, 0, 0)

// ---- init: order=-1, counts/flag=0 ----
__global__ void k_init(int* __restrict__ order, int* __restrict__ counts) {
  int i = blockIdx.x * 256 + threadIdx.x;
  if (i < ORDER_N) order[i] = -1;
  if (i < 64) counts[i] = 0;
}

// ---- detect atom_mask dtype: bit1 = uint8-packed, bit2 = float32 ----
__global__ void k_detect(const unsigned int* __restrict__ mask, int* __restrict__ flag) {
  unsigned int v = mask[threadIdx.x];   // first 1KB: safe for any elem width
  int b = 0;
  if (v == 0x3F800000u) b = 2;
  else if (v > 1u) b = 1;
  if (b) atomicOr(flag, b);
}

// ---- featurize: frame, rotate, mask -> crd[t][42]; LDS-aggregated aa histogram ----
__global__ void k_feat(const float* __restrict__ pos14, const int* __restrict__ aa,
                       const void* __restrict__ maskp, float* __restrict__ crd,
                       int* __restrict__ counts) {
  __shared__ int hist[NAA];
  const int tid = threadIdx.x;
  if (tid < NAA) hist[tid] = 0;
  __syncthreads();
  const int t = blockIdx.x * 256 + tid;   // grid exact: 256*256 == TOKENS
  const int fl = counts[32];
  const float* p = pos14 + (size_t)t * 42;
  float px[14], py[14], pz[14];
#pragma unroll
  for (int a = 0; a < 14; ++a) { px[a] = p[a*3]; py[a] = p[a*3+1]; pz[a] = p[a*3+2]; }
  float cx = px[1], cy = py[1], cz = pz[1];
  float v1x = px[2]-cx, v1y = py[2]-cy, v1z = pz[2]-cz;
  float n1 = sqrtf(v1x*v1x + v1y*v1y + v1z*v1z);
  float i1 = 1.f / (n1 + EPSF);
  float e1x = v1x*i1, e1y = v1y*i1, e1z = v1z*i1;
  float v2x = px[0]-cx, v2y = py[0]-cy, v2z = pz[0]-cz;
  float d12 = e1x*v2x + e1y*v2y + e1z*v2z;
  float u2x = v2x - d12*e1x, u2y = v2y - d12*e1y, u2z = v2z - d12*e1z;
  float n2 = sqrtf(u2x*u2x + u2y*u2y + u2z*u2z);
  float i2 = 1.f / (n2 + EPSF);
  float e2x = u2x*i2, e2y = u2y*i2, e2z = u2z*i2;
  float e3x = e1y*e2z - e1z*e2y;
  float e3y = e1z*e2x - e1x*e2z;
  float e3z = e1x*e2y - e1y*e2x;
  float* o = crd + (size_t)t * 42;
#pragma unroll
  for (int a = 0; a < 14; ++a) {
    bool mv;
    size_t mi = (size_t)t * 14 + a;
    if (fl & 2)      mv = ((const float*)maskp)[mi] != 0.f;
    else if (fl & 1) mv = ((const unsigned char*)maskp)[mi] != 0;
    else             mv = ((const int*)maskp)[mi] != 0;
    float qx = px[a]-cx, qy = py[a]-cy, qz = pz[a]-cz;
    o[a*3+0] = mv ? (e1x*qx + e1y*qy + e1z*qz) : 0.f;
    o[a*3+1] = mv ? (e2x*qx + e2y*qy + e2z*qz) : 0.f;
    o[a*3+2] = mv ? (e3x*qx + e3y*qy + e3z*qz) : 0.f;
  }
  atomicAdd(&hist[aa[t]], 1);              // LDS atomic, 21 banks
  __syncthreads();
  if (tid < NAA && hist[tid]) atomicAdd(&counts[tid], hist[tid]);  // 21/block global
}

// ---- padded group offsets (pad each aa group to multiple of 64) ----
__global__ void k_offsets(const int* __restrict__ counts, int* __restrict__ cnt2) {
  if (threadIdx.x == 0) {
    int run = 0;
    for (int a = 0; a < NAA; ++a) { cnt2[a] = run; run += ((counts[a] + 63) >> 6) << 6; }
  }
}

// ---- scatter tokens into aa-grouped order; LDS rank + per-bin base grab ----
__global__ void k_scatter(const int* __restrict__ aa, int* __restrict__ cnt2,
                          int* __restrict__ order) {
  __shared__ int lh[NAA], base[NAA];
  const int tid = threadIdx.x;
  if (tid < NAA) lh[tid] = 0;
  __syncthreads();
  const int t = blockIdx.x * 256 + tid;   // grid exact
  const int a = aa[t];
  const int r = atomicAdd(&lh[a], 1);     // LDS: within-block rank
  __syncthreads();
  if (tid < NAA) base[tid] = lh[tid] ? atomicAdd(&cnt2[tid], lh[tid]) : 0;
  __syncthreads();
  order[base[a] + r] = t;
}

// ---- T1[a][c] = embed[a] @ w1[882:] + b1 ----
__global__ void k_T1(const float* __restrict__ embed, const float* __restrict__ w1,
                     const float* __restrict__ b1, float* __restrict__ T1) {
  int idx = blockIdx.x * 256 + threadIdx.x;   // 84*256 == 21*1024 exactly
  int a = idx >> 10, c = idx & 1023;
  float acc = b1[c];
  const float* e = embed + a * FEATD;
#pragma unroll 8
  for (int k = 0; k < FEATD; ++k)
    acc += e[k] * w1[(size_t)(882 + k) * L1OUT + c];
  T1[idx] = acc;
}

// ---- transpose W[K][N] fp32 -> WT[N][K] bf16 ----
__global__ void k_transpose(const float* __restrict__ W, unsigned short* __restrict__ WT,
                            int kbits, int N) {
  int idx = blockIdx.x * 256 + threadIdx.x;
  int K = 1 << kbits;
  int n = idx >> kbits, k = idx & (K - 1);
  WT[(size_t)n * K + k] = f2bf(W[(size_t)k * N + n]);
}

// ---- layer1: per 64-pos single-aa block, weight-stationary, fp32 vector ----
__global__ void k_layer1(const int* __restrict__ order, const int* __restrict__ aa_g,
                         const float* __restrict__ crd, const float* __restrict__ w1,
                         const float* __restrict__ T1, unsigned short* __restrict__ h1) {
  __shared__ int tokens[64];
  __shared__ int s_aa;
  __shared__ float crdl[64 * 42];
  __shared__ float Wl[42 * 132];   // stride 132 floats (pad)
  const int tid = threadIdx.x;
  const int pb = blockIdx.y;
  const int cc = blockIdx.x * 128;
  if (tid < 64) tokens[tid] = order[pb * 64 + tid];
  __syncthreads();
  if (tid == 0) {
    int a = -1;
    for (int i = 0; i < 64; ++i) if (tokens[i] >= 0) { a = aa_g[tokens[i]]; break; }
    s_aa = a;
  }
  __syncthreads();
  const int a = s_aa;
  if (a < 0) return;   // fully-dummy block (uniform)
  for (int idx = tid; idx < 64 * 42; idx += 256) {
    int pos = idx / 42, j = idx - pos * 42;
    int tok = tokens[pos];
    crdl[idx] = (tok >= 0) ? crd[(size_t)tok * 42 + j] : 0.f;
  }
  const float* wsrc = w1 + (size_t)a * 42 * L1OUT + cc;
  for (int idx = tid; idx < 42 * 128; idx += 256) {
    int j = idx >> 7, c = idx & 127;
    Wl[j * 132 + c] = wsrc[(size_t)j * L1OUT + c];
  }
  __syncthreads();
  const int posl = (tid >> 4) * 4;
  const int colb = (tid & 15) * 8;
  float acc[4][8];
  {
    const float* tb = T1 + a * L1OUT + cc + colb;
#pragma unroll
    for (int q = 0; q < 8; ++q) {
      float t = tb[q];
#pragma unroll
      for (int pp = 0; pp < 4; ++pp) acc[pp][q] = t;
    }
  }
  for (int j = 0; j < 42; ++j) {
    float4 wA = *(const float4*)&Wl[j * 132 + colb];
    float4 wB = *(const float4*)&Wl[j * 132 + colb + 4];
#pragma unroll
    for (int pp = 0; pp < 4; ++pp) {
      float cv = crdl[(posl + pp) * 42 + j];
      acc[pp][0] += cv * wA.x; acc[pp][1] += cv * wA.y;
      acc[pp][2] += cv * wA.z; acc[pp][3] += cv * wA.w;
      acc[pp][4] += cv * wB.x; acc[pp][5] += cv * wB.y;
      acc[pp][6] += cv * wB.z; acc[pp][7] += cv * wB.w;
    }
  }
#pragma unroll
  for (int pp = 0; pp < 4; ++pp) {
    int tok = tokens[posl + pp];
    if (tok < 0) continue;
    unsigned short o8[8];
#pragma unroll
    for (int q = 0; q < 8; ++q) o8[q] = f2bf(fmaxf(acc[pp][q], 0.f));
    *(uint4*)&h1[(size_t)tok * L1OUT + cc + colb] = *(const uint4*)o8;
  }
}

// ---- bf16 MFMA GEMM: [65536 x K] @ [K x 512] (+bias, relu?) ----
// BM=BN=128, BK=64; 4 waves, each 64x64 via 4x4 frags of 16x16x32.
// Staging: global_load_lds dwordx4 (wave-uniform LDS base + lane*16).
// XOR swizzle on the FETCH side: LDS (row, chunk c) holds global chunk
// c ^ (row&7), so ds_read_b128 spreads all 32 banks (2-way only = free).
template<int K, bool RELU, bool OUTBF16>
__global__ void k_gemm(const unsigned short* __restrict__ A,
                       const unsigned short* __restrict__ BT,  // [512][K] bf16
                       const float* __restrict__ bias, void* __restrict__ outp) {
  constexpr int N = 512;
  __shared__ unsigned short Al[128 * 64];
  __shared__ unsigned short Bl[128 * 64];
  const int tid = threadIdx.x;
  const int lane = tid & 63;
  const int wid = tid >> 6;
  const int wm = (wid & 1) * 64;
  const int wn = (wid >> 1) * 64;
  const int m0 = blockIdx.y * 128;
  const int n0 = blockIdx.x * 128;
  // staging geometry: wave w stages rows [w*32, w*32+32) of both tiles,
  // 4 issues of 8 rows (1024B) each. lane L -> row += L/8, global chunk
  // gc = (L&7) ^ (L/8)  [xor swizzle: lds chunk L&7 holds global chunk gc]
  const int srow = wid * 32;
  const int lrow = lane >> 3;
  const int gcol = ((lane & 7) ^ lrow) * 8;   // shorts
  floatx4 acc[4][4] = {};
  for (int k0 = 0; k0 < K; k0 += 64) {
#pragma unroll
    for (int i = 0; i < 4; ++i) {
      const int row = srow + i * 8;
      GLDS16(&A [(size_t)(m0 + row + lrow) * K + k0 + gcol], &Al[row * 64]);
      GLDS16(&BT[(size_t)(n0 + row + lrow) * K + k0 + gcol], &Bl[row * 64]);
    }
    __syncthreads();
#pragma unroll
    for (int kk = 0; kk < 2; ++kk) {
      short8 af[4], bf[4];
      const int kc = kk * 4 + (lane >> 4);        // k-chunk index (16B units)
      const int swz = (kc ^ (lane & 7)) * 8;      // swizzled short offset
#pragma unroll
      for (int i = 0; i < 4; ++i) {
        af[i] = *(const short8*)&Al[(wm + i * 16 + (lane & 15)) * 64 + swz];
        bf[i] = *(const short8*)&Bl[(wn + i * 16 + (lane & 15)) * 64 + swz];
      }
#pragma unroll
      for (int i = 0; i < 4; ++i)
#pragma unroll
        for (int j = 0; j < 4; ++j)
          acc[i][j] = __builtin_amdgcn_mfma_f32_16x16x32_bf16(af[i], bf[j], acc[i][j], 0, 0, 0);
    }
    __syncthreads();
  }
#pragma unroll
  for (int i = 0; i < 4; ++i) {
    int rbase = m0 + wm + i * 16 + ((lane >> 4) << 2);
#pragma unroll
    for (int j = 0; j < 4; ++j) {
      int col = n0 + wn + j * 16 + (lane & 15);
      float bv = bias[col];
#pragma unroll
      for (int r = 0; r < 4; ++r) {
        float v = acc[i][j][r] + bv;
        if (RELU) v = fmaxf(v, 0.f);
        size_t off = (size_t)(rbase + r) * N + col;
        if (OUTBF16) ((unsigned short*)outp)[off] = f2bf(v);
        else ((float*)outp)[off] = v;
      }
    }
  }
}

extern "C" void kernel_launch(void* const* d_in, const int* in_sizes, int n_in,
                              void* d_out, int out_size, void* d_ws, size_t ws_size,
                              hipStream_t stream) {
  const int*   aa    = (const int*)d_in[0];
  const float* pos14 = (const float*)d_in[1];
  const void*  mask  = d_in[2];
  const float* embed = (const float*)d_in[3];
  const float* w1    = (const float*)d_in[4];
  const float* b1    = (const float*)d_in[5];
  const float* w2    = (const float*)d_in[6];
  const float* b2    = (const float*)d_in[7];
  const float* w3    = (const float*)d_in[8];
  const float* b3    = (const float*)d_in[9];
  const float* w4    = (const float*)d_in[10];
  const float* b4    = (const float*)d_in[11];

  char* ws = (char*)d_ws;
  size_t o = 0;
  auto alloc = [&](size_t b) { size_t r = o; o += (b + 255) & ~(size_t)255; return r; };
  unsigned short* w2T = (unsigned short*)(ws + alloc((size_t)512 * 1024 * 2));
  unsigned short* w3T = (unsigned short*)(ws + alloc((size_t)512 * 512 * 2));
  unsigned short* w4T = (unsigned short*)(ws + alloc((size_t)512 * 512 * 2));
  float* T1   = (float*)(ws + alloc((size_t)NAA * 1024 * 4));
  float* crd  = (float*)(ws + alloc((size_t)TOKENS * 42 * 4));
  int* counts = (int*)(ws + alloc(64 * 4));          // [32] doubles as dtype flag
  int* cnt2   = (int*)(ws + alloc(64 * 4));
  int* order  = (int*)(ws + alloc((size_t)ORDER_N * 4));
  unsigned short* h1 = (unsigned short*)(ws + alloc((size_t)TOKENS * 1024 * 2));
  unsigned short* h2 = (unsigned short*)(ws + alloc((size_t)TOKENS * 512 * 2));
  unsigned short* h3 = h1;  // reuse h1 buffer for h3

  k_init<<<262, 256, 0, stream>>>(order, counts);
  k_detect<<<1, 256, 0, stream>>>((const unsigned int*)mask, &counts[32]);
  k_transpose<<<2048, 256, 0, stream>>>(w2, w2T, 10, 512);
  k_transpose<<<1024, 256, 0, stream>>>(w3, w3T, 9, 512);
  k_transpose<<<1024, 256, 0, stream>>>(w4, w4T, 9, 512);
  k_T1<<<84, 256, 0, stream>>>(embed, w1, b1, T1);
  k_feat<<<256, 256, 0, stream>>>(pos14, aa, mask, crd, counts);
  k_offsets<<<1, 64, 0, stream>>>(counts, cnt2);
  k_scatter<<<256, 256, 0, stream>>>(aa, cnt2, order);
  k_layer1<<<dim3(8, 1045), 256, 0, stream>>>(order, aa, crd, w1, T1, h1);
  k_gemm<1024, true,  true ><<<dim3(4, 512), 256, 0, stream>>>(h1, w2T, b2, h2);
  k_gemm<512,  true,  true ><<<dim3(4, 512), 256, 0, stream>>>(h2, w3T, b3, h3);
  k_gemm<512,  false, false><<<dim3(4, 512), 256, 0, stream>>>(h3, w4T, b4, d_out);
}

// Round 3
// 469.075 us; speedup vs baseline: 1.7657x; 1.1147x over previous
//
#include <hip/hip_runtime.h>
#include <hip/hip_bf16.h>

// PerResidueEncoder: frame+crd featurize -> sparse layer1 (aa-grouped) ->
// 3x bf16 MFMA GEMM (relu, relu, linear).
// R1: LDS-aggregated histograms; GEMM staging via global_load_lds w=16 + XOR swizzle.
// R2: layer1 moved to MFMA (was fp32 vector, 126us VALU/LDS-bound):
//     crd stored bf16 padded K=64, w1 pre-transposed [aa][col][k] bf16,
//     A rows gathered per-lane via global_load_lds.

typedef __attribute__((ext_vector_type(8))) short short8;
typedef __attribute__((ext_vector_type(4))) float floatx4;

#define TOKENS 65536
#define FEATD 512
#define L1OUT 1024
#define NAA 21
#define EPSF 1e-6f
#define ORDER_N 66880   // 1045 blocks * 64 slots >= 65536 + 21*63

static __device__ __forceinline__ unsigned short f2bf(float f) {
  union { float f; unsigned int u; } v; v.f = f;
  unsigned int u = v.u;
  return (unsigned short)((u + 0x7FFFu + ((u >> 16) & 1u)) >> 16);
}

#define GLDS16(g, l) __builtin_amdgcn_global_load_lds(                        \
    (const __attribute__((address_space(1))) unsigned int*)(g),               \
    (__attribute__((address_space(3))) unsigned int*)(l), 16, 0, 0)

// ---- init: order=-1, counts/flag=0 ----
__global__ void k_init(int* __restrict__ order, int* __restrict__ counts) {
  int i = blockIdx.x * 256 + threadIdx.x;
  if (i < ORDER_N) order[i] = -1;
  if (i < 64) counts[i] = 0;
}

// ---- detect atom_mask dtype: bit1 = uint8-packed, bit2 = float32 ----
__global__ void k_detect(const unsigned int* __restrict__ mask, int* __restrict__ flag) {
  unsigned int v = mask[threadIdx.x];   // first 1KB: safe for any elem width
  int b = 0;
  if (v == 0x3F800000u) b = 2;
  else if (v > 1u) b = 1;
  if (b) atomicOr(flag, b);
}

// ---- featurize: frame, rotate, mask -> crdb[t][64] bf16 (42 real + 22 zero pad);
//      LDS-aggregated aa histogram ----
__global__ void k_feat(const float* __restrict__ pos14, const int* __restrict__ aa,
                       const void* __restrict__ maskp, unsigned short* __restrict__ crdb,
                       int* __restrict__ counts) {
  __shared__ int hist[NAA];
  const int tid = threadIdx.x;
  if (tid < NAA) hist[tid] = 0;
  __syncthreads();
  const int t = blockIdx.x * 256 + tid;   // grid exact: 256*256 == TOKENS
  const int fl = counts[32];
  const float* p = pos14 + (size_t)t * 42;
  float px[14], py[14], pz[14];
#pragma unroll
  for (int a = 0; a < 14; ++a) { px[a] = p[a*3]; py[a] = p[a*3+1]; pz[a] = p[a*3+2]; }
  float cx = px[1], cy = py[1], cz = pz[1];
  float v1x = px[2]-cx, v1y = py[2]-cy, v1z = pz[2]-cz;
  float n1 = sqrtf(v1x*v1x + v1y*v1y + v1z*v1z);
  float i1 = 1.f / (n1 + EPSF);
  float e1x = v1x*i1, e1y = v1y*i1, e1z = v1z*i1;
  float v2x = px[0]-cx, v2y = py[0]-cy, v2z = pz[0]-cz;
  float d12 = e1x*v2x + e1y*v2y + e1z*v2z;
  float u2x = v2x - d12*e1x, u2y = v2y - d12*e1y, u2z = v2z - d12*e1z;
  float n2 = sqrtf(u2x*u2x + u2y*u2y + u2z*u2z);
  float i2 = 1.f / (n2 + EPSF);
  float e2x = u2x*i2, e2y = u2y*i2, e2z = u2z*i2;
  float e3x = e1y*e2z - e1z*e2y;
  float e3y = e1z*e2x - e1x*e2z;
  float e3z = e1x*e2y - e1y*e2x;
  unsigned short ob[64];
#pragma unroll
  for (int a = 0; a < 14; ++a) {
    bool mv;
    size_t mi = (size_t)t * 14 + a;
    if (fl & 2)      mv = ((const float*)maskp)[mi] != 0.f;
    else if (fl & 1) mv = ((const unsigned char*)maskp)[mi] != 0;
    else             mv = ((const int*)maskp)[mi] != 0;
    float qx = px[a]-cx, qy = py[a]-cy, qz = pz[a]-cz;
    ob[a*3+0] = mv ? f2bf(e1x*qx + e1y*qy + e1z*qz) : 0;
    ob[a*3+1] = mv ? f2bf(e2x*qx + e2y*qy + e2z*qz) : 0;
    ob[a*3+2] = mv ? f2bf(e3x*qx + e3y*qy + e3z*qz) : 0;
  }
#pragma unroll
  for (int k = 42; k < 64; ++k) ob[k] = 0;
  uint4* dst = (uint4*)&crdb[(size_t)t * 64];
#pragma unroll
  for (int q = 0; q < 8; ++q) dst[q] = ((const uint4*)ob)[q];
  atomicAdd(&hist[aa[t]], 1);              // LDS atomic, 21 banks
  __syncthreads();
  if (tid < NAA && hist[tid]) atomicAdd(&counts[tid], hist[tid]);  // 21/block global
}

// ---- padded group offsets (pad each aa group to multiple of 64) ----
__global__ void k_offsets(const int* __restrict__ counts, int* __restrict__ cnt2) {
  if (threadIdx.x == 0) {
    int run = 0;
    for (int a = 0; a < NAA; ++a) { cnt2[a] = run; run += ((counts[a] + 63) >> 6) << 6; }
  }
}

// ---- scatter tokens into aa-grouped order; LDS rank + per-bin base grab ----
__global__ void k_scatter(const int* __restrict__ aa, int* __restrict__ cnt2,
                          int* __restrict__ order) {
  __shared__ int lh[NAA], base[NAA];
  const int tid = threadIdx.x;
  if (tid < NAA) lh[tid] = 0;
  __syncthreads();
  const int t = blockIdx.x * 256 + tid;   // grid exact
  const int a = aa[t];
  const int r = atomicAdd(&lh[a], 1);     // LDS: within-block rank
  __syncthreads();
  if (tid < NAA) base[tid] = lh[tid] ? atomicAdd(&cnt2[tid], lh[tid]) : 0;
  __syncthreads();
  order[base[a] + r] = t;
}

// ---- T1[a][c] = embed[a] @ w1[882:] + b1 ----
__global__ void k_T1(const float* __restrict__ embed, const float* __restrict__ w1,
                     const float* __restrict__ b1, float* __restrict__ T1) {
  int idx = blockIdx.x * 256 + threadIdx.x;   // 84*256 == 21*1024 exactly
  int a = idx >> 10, c = idx & 1023;
  float acc = b1[c];
  const float* e = embed + a * FEATD;
#pragma unroll 8
  for (int k = 0; k < FEATD; ++k)
    acc += e[k] * w1[(size_t)(882 + k) * L1OUT + c];
  T1[idx] = acc;
}

// ---- w1T2[a][c][k] = bf16(w1[a*42+k][c]), k<42, else 0 (K padded to 64) ----
__global__ void k_w1T(const float* __restrict__ w1, unsigned short* __restrict__ w1T2) {
  int idx = blockIdx.x * 256 + threadIdx.x;   // 84*256 == 21*1024
  int a = idx >> 10, c = idx & 1023;
  unsigned short tmp[64];
#pragma unroll
  for (int k = 0; k < 64; ++k)
    tmp[k] = (k < 42) ? f2bf(w1[(size_t)(a * 42 + k) * L1OUT + c]) : 0;
  uint4* dst = (uint4*)&w1T2[(size_t)idx * 64];
#pragma unroll
  for (int q = 0; q < 8; ++q) dst[q] = ((const uint4*)tmp)[q];
}

// ---- transpose W[K][N] fp32 -> WT[N][K] bf16 ----
__global__ void k_transpose(const float* __restrict__ W, unsigned short* __restrict__ WT,
                            int kbits, int N) {
  int idx = blockIdx.x * 256 + threadIdx.x;
  int K = 1 << kbits;
  int n = idx >> kbits, k = idx & (K - 1);
  WT[(size_t)n * K + k] = f2bf(W[(size_t)k * N + n]);
}

// ---- layer1 (MFMA): per 64-token single-aa block x 256 cols, K=64 bf16 ----
// A = gathered crdb rows (global_load_lds per-lane gather), B = w1T2 slice.
__global__ void k_layer1(const int* __restrict__ order, const int* __restrict__ aa_g,
                         const unsigned short* __restrict__ crdb,
                         const unsigned short* __restrict__ w1T2,
                         const float* __restrict__ T1, unsigned short* __restrict__ h1) {
  __shared__ int tokens[64];
  __shared__ int s_aa;
  __shared__ unsigned short Al[64 * 64];
  __shared__ unsigned short Bl[256 * 64];
  const int tid = threadIdx.x;
  const int lane = tid & 63;
  const int wid = tid >> 6;
  const int pb = blockIdx.y;
  const int cc = blockIdx.x * 256;
  if (tid < 64) tokens[tid] = order[pb * 64 + tid];
  __syncthreads();
  if (tid == 0) {
    int a = -1;
    for (int i = 0; i < 64; ++i) if (tokens[i] >= 0) { a = aa_g[tokens[i]]; break; }
    s_aa = a;
  }
  __syncthreads();
  const int a = s_aa;
  if (a < 0) return;   // fully-dummy block (block-uniform)
  const int lrow = lane >> 3;
  const int gch = (lane & 7) ^ lrow;   // xor swizzle: lds chunk L&7 <- global chunk gch
  // A: wave w stages token rows [w*16, w*16+16), 2 calls of 8 rows
#pragma unroll
  for (int i = 0; i < 2; ++i) {
    int row = wid * 16 + i * 8;
    int tok = tokens[row + lrow]; if (tok < 0) tok = 0;   // dummy -> garbage, skipped at store
    GLDS16(&crdb[(size_t)tok * 64 + gch * 8], &Al[row * 64]);
  }
  // B: wave w stages col rows [w*64, w*64+64), 8 calls
  const unsigned short* bsrc = w1T2 + ((size_t)a * L1OUT + cc) * 64;
#pragma unroll
  for (int i = 0; i < 8; ++i) {
    int row = wid * 64 + i * 8;
    GLDS16(&bsrc[(size_t)(row + lrow) * 64 + gch * 8], &Bl[row * 64]);
  }
  __syncthreads();
  const int wn = wid * 64;
  floatx4 acc[4][4] = {};
#pragma unroll
  for (int kk = 0; kk < 2; ++kk) {
    short8 af[4], bfr[4];
    const int kc = kk * 4 + (lane >> 4);     // 16B k-chunk index
#pragma unroll
    for (int i = 0; i < 4; ++i) {
      int ar = i * 16 + (lane & 15);
      af[i]  = *(const short8*)&Al[ar * 64 + (kc ^ (ar & 7)) * 8];
      int br = wn + i * 16 + (lane & 15);
      bfr[i] = *(const short8*)&Bl[br * 64 + (kc ^ (br & 7)) * 8];
    }
#pragma unroll
    for (int i = 0; i < 4; ++i)
#pragma unroll
      for (int j = 0; j < 4; ++j)
        acc[i][j] = __builtin_amdgcn_mfma_f32_16x16x32_bf16(af[i], bfr[j], acc[i][j], 0, 0, 0);
  }
#pragma unroll
  for (int i = 0; i < 4; ++i) {
    int tb = i * 16 + ((lane >> 4) << 2);
#pragma unroll
    for (int j = 0; j < 4; ++j) {
      int colg = cc + wn + j * 16 + (lane & 15);
      float bv = T1[a * L1OUT + colg];
#pragma unroll
      for (int r = 0; r < 4; ++r) {
        int tok = tokens[tb + r];
        if (tok < 0) continue;
        h1[(size_t)tok * L1OUT + colg] = f2bf(fmaxf(acc[i][j][r] + bv, 0.f));
      }
    }
  }
}

// ---- bf16 MFMA GEMM: [65536 x K] @ [K x 512] (+bias, relu?) ----
// BM=BN=128, BK=64; 4 waves, each 64x64 via 4x4 frags of 16x16x32.
// Staging: global_load_lds dwordx4, XOR chunk swizzle on the fetch side.
template<int K, bool RELU, bool OUTBF16>
__global__ void k_gemm(const unsigned short* __restrict__ A,
                       const unsigned short* __restrict__ BT,  // [512][K] bf16
                       const float* __restrict__ bias, void* __restrict__ outp) {
  constexpr int N = 512;
  __shared__ unsigned short Al[128 * 64];
  __shared__ unsigned short Bl[128 * 64];
  const int tid = threadIdx.x;
  const int lane = tid & 63;
  const int wid = tid >> 6;
  const int wm = (wid & 1) * 64;
  const int wn = (wid >> 1) * 64;
  const int m0 = blockIdx.y * 128;
  const int n0 = blockIdx.x * 128;
  const int srow = wid * 32;
  const int lrow = lane >> 3;
  const int gcol = ((lane & 7) ^ lrow) * 8;   // shorts
  floatx4 acc[4][4] = {};
  for (int k0 = 0; k0 < K; k0 += 64) {
#pragma unroll
    for (int i = 0; i < 4; ++i) {
      const int row = srow + i * 8;
      GLDS16(&A [(size_t)(m0 + row + lrow) * K + k0 + gcol], &Al[row * 64]);
      GLDS16(&BT[(size_t)(n0 + row + lrow) * K + k0 + gcol], &Bl[row * 64]);
    }
    __syncthreads();
#pragma unroll
    for (int kk = 0; kk < 2; ++kk) {
      short8 af[4], bfr[4];
      const int kc = kk * 4 + (lane >> 4);        // k-chunk index (16B units)
      const int swz = (kc ^ (lane & 7)) * 8;      // swizzled short offset
#pragma unroll
      for (int i = 0; i < 4; ++i) {
        af[i]  = *(const short8*)&Al[(wm + i * 16 + (lane & 15)) * 64 + swz];
        bfr[i] = *(const short8*)&Bl[(wn + i * 16 + (lane & 15)) * 64 + swz];
      }
#pragma unroll
      for (int i = 0; i < 4; ++i)
#pragma unroll
        for (int j = 0; j < 4; ++j)
          acc[i][j] = __builtin_amdgcn_mfma_f32_16x16x32_bf16(af[i], bfr[j], acc[i][j], 0, 0, 0);
    }
    __syncthreads();
  }
#pragma unroll
  for (int i = 0; i < 4; ++i) {
    int rbase = m0 + wm + i * 16 + ((lane >> 4) << 2);
#pragma unroll
    for (int j = 0; j < 4; ++j) {
      int col = n0 + wn + j * 16 + (lane & 15);
      float bv = bias[col];
#pragma unroll
      for (int r = 0; r < 4; ++r) {
        float v = acc[i][j][r] + bv;
        if (RELU) v = fmaxf(v, 0.f);
        size_t off = (size_t)(rbase + r) * N + col;
        if (OUTBF16) ((unsigned short*)outp)[off] = f2bf(v);
        else ((float*)outp)[off] = v;
      }
    }
  }
}

extern "C" void kernel_launch(void* const* d_in, const int* in_sizes, int n_in,
                              void* d_out, int out_size, void* d_ws, size_t ws_size,
                              hipStream_t stream) {
  const int*   aa    = (const int*)d_in[0];
  const float* pos14 = (const float*)d_in[1];
  const void*  mask  = d_in[2];
  const float* embed = (const float*)d_in[3];
  const float* w1    = (const float*)d_in[4];
  const float* b1    = (const float*)d_in[5];
  const float* w2    = (const float*)d_in[6];
  const float* b2    = (const float*)d_in[7];
  const float* w3    = (const float*)d_in[8];
  const float* b3    = (const float*)d_in[9];
  const float* w4    = (const float*)d_in[10];
  const float* b4    = (const float*)d_in[11];

  char* ws = (char*)d_ws;
  size_t o = 0;
  auto alloc = [&](size_t b) { size_t r = o; o += (b + 255) & ~(size_t)255; return r; };
  unsigned short* w2T = (unsigned short*)(ws + alloc((size_t)512 * 1024 * 2));
  unsigned short* w3T = (unsigned short*)(ws + alloc((size_t)512 * 512 * 2));
  unsigned short* w4T = (unsigned short*)(ws + alloc((size_t)512 * 512 * 2));
  unsigned short* w1T2 = (unsigned short*)(ws + alloc((size_t)NAA * 1024 * 64 * 2));
  float* T1   = (float*)(ws + alloc((size_t)NAA * 1024 * 4));
  unsigned short* crdb = (unsigned short*)(ws + alloc((size_t)TOKENS * 64 * 2));
  int* counts = (int*)(ws + alloc(64 * 4));          // [32] doubles as dtype flag
  int* cnt2   = (int*)(ws + alloc(64 * 4));
  int* order  = (int*)(ws + alloc((size_t)ORDER_N * 4));
  unsigned short* h1 = (unsigned short*)(ws + alloc((size_t)TOKENS * 1024 * 2));
  unsigned short* h2 = (unsigned short*)(ws + alloc((size_t)TOKENS * 512 * 2));
  unsigned short* h3 = h1;  // reuse h1 buffer for h3

  k_init<<<262, 256, 0, stream>>>(order, counts);
  k_detect<<<1, 256, 0, stream>>>((const unsigned int*)mask, &counts[32]);
  k_transpose<<<2048, 256, 0, stream>>>(w2, w2T, 10, 512);
  k_transpose<<<1024, 256, 0, stream>>>(w3, w3T, 9, 512);
  k_transpose<<<1024, 256, 0, stream>>>(w4, w4T, 9, 512);
  k_w1T<<<84, 256, 0, stream>>>(w1, w1T2);
  k_T1<<<84, 256, 0, stream>>>(embed, w1, b1, T1);
  k_feat<<<256, 256, 0, stream>>>(pos14, aa, mask, crdb, counts);
  k_offsets<<<1, 64, 0, stream>>>(counts, cnt2);
  k_scatter<<<256, 256, 0, stream>>>(aa, cnt2, order);
  k_layer1<<<dim3(4, 1045), 256, 0, stream>>>(order, aa, crdb, w1T2, T1, h1);
  k_gemm<1024, true,  true ><<<dim3(4, 512), 256, 0, stream>>>(h1, w2T, b2, h2);
  k_gemm<512,  true,  true ><<<dim3(4, 512), 256, 0, stream>>>(h2, w3T, b3, h3);
  k_gemm<512,  false, false><<<dim3(4, 512), 256, 0, stream>>>(h3, w4T, b4, d_out);
}

// Round 4
// 424.203 us; speedup vs baseline: 1.9524x; 1.1058x over previous
//
#include <hip/hip_runtime.h>
#include <hip/hip_bf16.h>

// PerResidueEncoder: frame+crd featurize -> sparse layer1 (aa-grouped, MFMA) ->
// 3x bf16 MFMA GEMM (relu, relu, linear).
// R1: LDS-aggregated histograms; global_load_lds w=16 + XOR swizzle staging.
// R2: layer1 on MFMA (crd bf16 K=64-padded, w1 pre-transposed per-aa).
// R3: XCD-aware n-within-m GEMM block swizzle (A-tile fetched once per XCD,
//     was 2x overfetch = 265MB); merged prep kernels (14 -> 9 launches).

typedef __attribute__((ext_vector_type(8))) short short8;
typedef __attribute__((ext_vector_type(4))) float floatx4;

#define TOKENS 65536
#define FEATD 512
#define L1OUT 1024
#define NAA 21
#define EPSF 1e-6f
#define ORDER_N 66880   // 1045 blocks * 64 slots >= 65536 + 21*63

static __device__ __forceinline__ unsigned short f2bf(float f) {
  union { float f; unsigned int u; } v; v.f = f;
  unsigned int u = v.u;
  return (unsigned short)((u + 0x7FFFu + ((u >> 16) & 1u)) >> 16);
}

#define GLDS16(g, l) __builtin_amdgcn_global_load_lds(                        \
    (const __attribute__((address_space(1))) unsigned int*)(g),               \
    (__attribute__((address_space(3))) unsigned int*)(l), 16, 0, 0)

// ---- init: order=-1; block 0 zeroes counts then detects mask dtype ----
// flag (counts[32]): bit1 = uint8-packed, bit2 = float32
__global__ void k_init(int* __restrict__ order, int* __restrict__ counts,
                       const unsigned int* __restrict__ mask) {
  int i = blockIdx.x * 256 + threadIdx.x;
  if (i < ORDER_N) order[i] = -1;
  if (blockIdx.x == 0) {
    if (threadIdx.x < 64) counts[threadIdx.x] = 0;
    __syncthreads();
    unsigned int v = mask[threadIdx.x];   // first 1KB: safe for any elem width
    int b = 0;
    if (v == 0x3F800000u) b = 2;
    else if (v > 1u) b = 1;
    if (b) atomicOr(&counts[32], b);
  }
}

// ---- prep (range-partitioned): 3x weight transpose fp32->bf16 [N][K],
//      w1T2[a][c][k] (K padded 42->64), T1[a][c] = embed[a]@w1[882:]+b1 ----
__global__ void k_prep(const float* __restrict__ w2, unsigned short* __restrict__ w2T,
                       const float* __restrict__ w3, unsigned short* __restrict__ w3T,
                       const float* __restrict__ w4, unsigned short* __restrict__ w4T,
                       const float* __restrict__ w1, unsigned short* __restrict__ w1T2,
                       const float* __restrict__ embed, const float* __restrict__ b1,
                       float* __restrict__ T1) {
  const int b = blockIdx.x;
  const int tid = threadIdx.x;
  if (b < 4096) {   // transposes
    const float* W; unsigned short* WT; int kbits, N, idx;
    if (b < 2048)      { W = w2; WT = w2T; kbits = 10; N = 512; idx = b * 256 + tid; }
    else if (b < 3072) { W = w3; WT = w3T; kbits = 9;  N = 512; idx = (b - 2048) * 256 + tid; }
    else               { W = w4; WT = w4T; kbits = 9;  N = 512; idx = (b - 3072) * 256 + tid; }
    int K = 1 << kbits;
    int n = idx >> kbits, k = idx & (K - 1);
    WT[(size_t)n * K + k] = f2bf(W[(size_t)k * N + n]);
  } else if (b < 4180) {   // w1T2: 84 blocks over 21*1024
    int idx = (b - 4096) * 256 + tid;
    int a = idx >> 10, c = idx & 1023;
    unsigned short tmp[64];
#pragma unroll
    for (int k = 0; k < 64; ++k)
      tmp[k] = (k < 42) ? f2bf(w1[(size_t)(a * 42 + k) * L1OUT + c]) : 0;
    uint4* dst = (uint4*)&w1T2[(size_t)idx * 64];
#pragma unroll
    for (int q = 0; q < 8; ++q) dst[q] = ((const uint4*)tmp)[q];
  } else {   // T1: 84 blocks
    int idx = (b - 4180) * 256 + tid;
    int a = idx >> 10, c = idx & 1023;
    float acc = b1[c];
    const float* e = embed + a * FEATD;
#pragma unroll 8
    for (int k = 0; k < FEATD; ++k)
      acc += e[k] * w1[(size_t)(882 + k) * L1OUT + c];
    T1[idx] = acc;
  }
}

// ---- featurize: frame, rotate, mask -> crdb[t][64] bf16 (42 real + 22 pad);
//      LDS-aggregated aa histogram ----
__global__ void k_feat(const float* __restrict__ pos14, const int* __restrict__ aa,
                       const void* __restrict__ maskp, unsigned short* __restrict__ crdb,
                       int* __restrict__ counts) {
  __shared__ int hist[NAA];
  const int tid = threadIdx.x;
  if (tid < NAA) hist[tid] = 0;
  __syncthreads();
  const int t = blockIdx.x * 256 + tid;   // grid exact: 256*256 == TOKENS
  const int fl = counts[32];
  const float* p = pos14 + (size_t)t * 42;
  float px[14], py[14], pz[14];
#pragma unroll
  for (int a = 0; a < 14; ++a) { px[a] = p[a*3]; py[a] = p[a*3+1]; pz[a] = p[a*3+2]; }
  float cx = px[1], cy = py[1], cz = pz[1];
  float v1x = px[2]-cx, v1y = py[2]-cy, v1z = pz[2]-cz;
  float n1 = sqrtf(v1x*v1x + v1y*v1y + v1z*v1z);
  float i1 = 1.f / (n1 + EPSF);
  float e1x = v1x*i1, e1y = v1y*i1, e1z = v1z*i1;
  float v2x = px[0]-cx, v2y = py[0]-cy, v2z = pz[0]-cz;
  float d12 = e1x*v2x + e1y*v2y + e1z*v2z;
  float u2x = v2x - d12*e1x, u2y = v2y - d12*e1y, u2z = v2z - d12*e1z;
  float n2 = sqrtf(u2x*u2x + u2y*u2y + u2z*u2z);
  float i2 = 1.f / (n2 + EPSF);
  float e2x = u2x*i2, e2y = u2y*i2, e2z = u2z*i2;
  float e3x = e1y*e2z - e1z*e2y;
  float e3y = e1z*e2x - e1x*e2z;
  float e3z = e1x*e2y - e1y*e2x;
  unsigned short ob[64];
#pragma unroll
  for (int a = 0; a < 14; ++a) {
    bool mv;
    size_t mi = (size_t)t * 14 + a;
    if (fl & 2)      mv = ((const float*)maskp)[mi] != 0.f;
    else if (fl & 1) mv = ((const unsigned char*)maskp)[mi] != 0;
    else             mv = ((const int*)maskp)[mi] != 0;
    float qx = px[a]-cx, qy = py[a]-cy, qz = pz[a]-cz;
    ob[a*3+0] = mv ? f2bf(e1x*qx + e1y*qy + e1z*qz) : 0;
    ob[a*3+1] = mv ? f2bf(e2x*qx + e2y*qy + e2z*qz) : 0;
    ob[a*3+2] = mv ? f2bf(e3x*qx + e3y*qy + e3z*qz) : 0;
  }
#pragma unroll
  for (int k = 42; k < 64; ++k) ob[k] = 0;
  uint4* dst = (uint4*)&crdb[(size_t)t * 64];
#pragma unroll
  for (int q = 0; q < 8; ++q) dst[q] = ((const uint4*)ob)[q];
  atomicAdd(&hist[aa[t]], 1);              // LDS atomic, 21 banks
  __syncthreads();
  if (tid < NAA && hist[tid]) atomicAdd(&counts[tid], hist[tid]);  // 21/block global
}

// ---- padded group offsets (pad each aa group to multiple of 64) ----
__global__ void k_offsets(const int* __restrict__ counts, int* __restrict__ cnt2) {
  if (threadIdx.x == 0) {
    int run = 0;
    for (int a = 0; a < NAA; ++a) { cnt2[a] = run; run += ((counts[a] + 63) >> 6) << 6; }
  }
}

// ---- scatter tokens into aa-grouped order; LDS rank + per-bin base grab ----
__global__ void k_scatter(const int* __restrict__ aa, int* __restrict__ cnt2,
                          int* __restrict__ order) {
  __shared__ int lh[NAA], base[NAA];
  const int tid = threadIdx.x;
  if (tid < NAA) lh[tid] = 0;
  __syncthreads();
  const int t = blockIdx.x * 256 + tid;   // grid exact
  const int a = aa[t];
  const int r = atomicAdd(&lh[a], 1);     // LDS: within-block rank
  __syncthreads();
  if (tid < NAA) base[tid] = lh[tid] ? atomicAdd(&cnt2[tid], lh[tid]) : 0;
  __syncthreads();
  order[base[a] + r] = t;
}

// ---- layer1 (MFMA): per 64-token single-aa block x 256 cols, K=64 bf16 ----
__global__ void k_layer1(const int* __restrict__ order, const int* __restrict__ aa_g,
                         const unsigned short* __restrict__ crdb,
                         const unsigned short* __restrict__ w1T2,
                         const float* __restrict__ T1, unsigned short* __restrict__ h1) {
  __shared__ int tokens[64];
  __shared__ int s_aa;
  __shared__ unsigned short Al[64 * 64];
  __shared__ unsigned short Bl[256 * 64];
  const int tid = threadIdx.x;
  const int lane = tid & 63;
  const int wid = tid >> 6;
  const int pb = blockIdx.y;
  const int cc = blockIdx.x * 256;
  if (tid < 64) tokens[tid] = order[pb * 64 + tid];
  __syncthreads();
  if (tid == 0) {
    int a = -1;
    for (int i = 0; i < 64; ++i) if (tokens[i] >= 0) { a = aa_g[tokens[i]]; break; }
    s_aa = a;
  }
  __syncthreads();
  const int a = s_aa;
  if (a < 0) return;   // fully-dummy block (block-uniform)
  const int lrow = lane >> 3;
  const int gch = (lane & 7) ^ lrow;   // xor swizzle: lds chunk L&7 <- global chunk gch
#pragma unroll
  for (int i = 0; i < 2; ++i) {
    int row = wid * 16 + i * 8;
    int tok = tokens[row + lrow]; if (tok < 0) tok = 0;
    GLDS16(&crdb[(size_t)tok * 64 + gch * 8], &Al[row * 64]);
  }
  const unsigned short* bsrc = w1T2 + ((size_t)a * L1OUT + cc) * 64;
#pragma unroll
  for (int i = 0; i < 8; ++i) {
    int row = wid * 64 + i * 8;
    GLDS16(&bsrc[(size_t)(row + lrow) * 64 + gch * 8], &Bl[row * 64]);
  }
  __syncthreads();
  const int wn = wid * 64;
  floatx4 acc[4][4] = {};
#pragma unroll
  for (int kk = 0; kk < 2; ++kk) {
    short8 af[4], bfr[4];
    const int kc = kk * 4 + (lane >> 4);     // 16B k-chunk index
#pragma unroll
    for (int i = 0; i < 4; ++i) {
      int ar = i * 16 + (lane & 15);
      af[i]  = *(const short8*)&Al[ar * 64 + (kc ^ (ar & 7)) * 8];
      int br = wn + i * 16 + (lane & 15);
      bfr[i] = *(const short8*)&Bl[br * 64 + (kc ^ (br & 7)) * 8];
    }
#pragma unroll
    for (int i = 0; i < 4; ++i)
#pragma unroll
      for (int j = 0; j < 4; ++j)
        acc[i][j] = __builtin_amdgcn_mfma_f32_16x16x32_bf16(af[i], bfr[j], acc[i][j], 0, 0, 0);
  }
#pragma unroll
  for (int i = 0; i < 4; ++i) {
    int tb = i * 16 + ((lane >> 4) << 2);
#pragma unroll
    for (int j = 0; j < 4; ++j) {
      int colg = cc + wn + j * 16 + (lane & 15);
      float bv = T1[a * L1OUT + colg];
#pragma unroll
      for (int r = 0; r < 4; ++r) {
        int tok = tokens[tb + r];
        if (tok < 0) continue;
        h1[(size_t)tok * L1OUT + colg] = f2bf(fmaxf(acc[i][j][r] + bv, 0.f));
      }
    }
  }
}

// ---- bf16 MFMA GEMM: [65536 x K] @ [K x 512] (+bias, relu?) ----
// BM=BN=128, BK=64; 4 waves, each 64x64 via 4x4 frags of 16x16x32.
// Staging: global_load_lds dwordx4, XOR chunk swizzle on the fetch side.
// Grid: linear 2048, XCD-aware swizzle — per-XCD sequence walks the 4
// n-tiles of one m-tile consecutively, so the A-tile stays L2-hot and is
// fetched from HBM once (was 2x overfetch with n-fastest dispatch).
template<int K, bool RELU, bool OUTBF16>
__global__ void k_gemm(const unsigned short* __restrict__ A,
                       const unsigned short* __restrict__ BT,  // [512][K] bf16
                       const float* __restrict__ bias, void* __restrict__ outp) {
  constexpr int N = 512;
  __shared__ unsigned short Al[128 * 64];
  __shared__ unsigned short Bl[128 * 64];
  const int l = blockIdx.x;
  const int m0 = (((l >> 5) << 3) | (l & 7)) * 128;   // m-tile: 8 per XCD-pass
  const int n0 = ((l >> 3) & 3) * 128;                // n walks 0..3 per m on one XCD
  const int tid = threadIdx.x;
  const int lane = tid & 63;
  const int wid = tid >> 6;
  const int wm = (wid & 1) * 64;
  const int wn = (wid >> 1) * 64;
  const int srow = wid * 32;
  const int lrow = lane >> 3;
  const int gcol = ((lane & 7) ^ lrow) * 8;   // shorts
  floatx4 acc[4][4] = {};
  for (int k0 = 0; k0 < K; k0 += 64) {
#pragma unroll
    for (int i = 0; i < 4; ++i) {
      const int row = srow + i * 8;
      GLDS16(&A [(size_t)(m0 + row + lrow) * K + k0 + gcol], &Al[row * 64]);
      GLDS16(&BT[(size_t)(n0 + row + lrow) * K + k0 + gcol], &Bl[row * 64]);
    }
    __syncthreads();
#pragma unroll
    for (int kk = 0; kk < 2; ++kk) {
      short8 af[4], bfr[4];
      const int kc = kk * 4 + (lane >> 4);        // k-chunk index (16B units)
      const int swz = (kc ^ (lane & 7)) * 8;      // swizzled short offset
#pragma unroll
      for (int i = 0; i < 4; ++i) {
        af[i]  = *(const short8*)&Al[(wm + i * 16 + (lane & 15)) * 64 + swz];
        bfr[i] = *(const short8*)&Bl[(wn + i * 16 + (lane & 15)) * 64 + swz];
      }
#pragma unroll
      for (int i = 0; i < 4; ++i)
#pragma unroll
        for (int j = 0; j < 4; ++j)
          acc[i][j] = __builtin_amdgcn_mfma_f32_16x16x32_bf16(af[i], bfr[j], acc[i][j], 0, 0, 0);
    }
    __syncthreads();
  }
#pragma unroll
  for (int i = 0; i < 4; ++i) {
    int rbase = m0 + wm + i * 16 + ((lane >> 4) << 2);
#pragma unroll
    for (int j = 0; j < 4; ++j) {
      int col = n0 + wn + j * 16 + (lane & 15);
      float bv = bias[col];
#pragma unroll
      for (int r = 0; r < 4; ++r) {
        float v = acc[i][j][r] + bv;
        if (RELU) v = fmaxf(v, 0.f);
        size_t off = (size_t)(rbase + r) * N + col;
        if (OUTBF16) ((unsigned short*)outp)[off] = f2bf(v);
        else ((float*)outp)[off] = v;
      }
    }
  }
}

extern "C" void kernel_launch(void* const* d_in, const int* in_sizes, int n_in,
                              void* d_out, int out_size, void* d_ws, size_t ws_size,
                              hipStream_t stream) {
  const int*   aa    = (const int*)d_in[0];
  const float* pos14 = (const float*)d_in[1];
  const void*  mask  = d_in[2];
  const float* embed = (const float*)d_in[3];
  const float* w1    = (const float*)d_in[4];
  const float* b1    = (const float*)d_in[5];
  const float* w2    = (const float*)d_in[6];
  const float* b2    = (const float*)d_in[7];
  const float* w3    = (const float*)d_in[8];
  const float* b3    = (const float*)d_in[9];
  const float* w4    = (const float*)d_in[10];
  const float* b4    = (const float*)d_in[11];

  char* ws = (char*)d_ws;
  size_t o = 0;
  auto alloc = [&](size_t b) { size_t r = o; o += (b + 255) & ~(size_t)255; return r; };
  unsigned short* w2T = (unsigned short*)(ws + alloc((size_t)512 * 1024 * 2));
  unsigned short* w3T = (unsigned short*)(ws + alloc((size_t)512 * 512 * 2));
  unsigned short* w4T = (unsigned short*)(ws + alloc((size_t)512 * 512 * 2));
  unsigned short* w1T2 = (unsigned short*)(ws + alloc((size_t)NAA * 1024 * 64 * 2));
  float* T1   = (float*)(ws + alloc((size_t)NAA * 1024 * 4));
  unsigned short* crdb = (unsigned short*)(ws + alloc((size_t)TOKENS * 64 * 2));
  int* counts = (int*)(ws + alloc(64 * 4));          // [32] doubles as dtype flag
  int* cnt2   = (int*)(ws + alloc(64 * 4));
  int* order  = (int*)(ws + alloc((size_t)ORDER_N * 4));
  unsigned short* h1 = (unsigned short*)(ws + alloc((size_t)TOKENS * 1024 * 2));
  unsigned short* h2 = (unsigned short*)(ws + alloc((size_t)TOKENS * 512 * 2));
  unsigned short* h3 = h1;  // reuse h1 buffer for h3

  k_init<<<262, 256, 0, stream>>>(order, counts, (const unsigned int*)mask);
  k_prep<<<4264, 256, 0, stream>>>(w2, w2T, w3, w3T, w4, w4T, w1, w1T2, embed, b1, T1);
  k_feat<<<256, 256, 0, stream>>>(pos14, aa, mask, crdb, counts);
  k_offsets<<<1, 64, 0, stream>>>(counts, cnt2);
  k_scatter<<<256, 256, 0, stream>>>(aa, cnt2, order);
  k_layer1<<<dim3(4, 1045), 256, 0, stream>>>(order, aa, crdb, w1T2, T1, h1);
  k_gemm<1024, true,  true ><<<2048, 256, 0, stream>>>(h1, w2T, b2, h2);
  k_gemm<512,  true,  true ><<<2048, 256, 0, stream>>>(h2, w3T, b3, h3);
  k_gemm<512,  false, false><<<2048, 256, 0, stream>>>(h3, w4T, b4, d_out);
}